// Round 4
// baseline (377.902 us; speedup 1.0000x reference)
//
#include <hip/hip_runtime.h>
#include <hip/hip_bf16.h>
#include <math.h>

#define NTOT 8192
#define HB   4096
#define DIM  256
#define RANK_N (4096*19)
#define NORM_BLOCKS (NTOT/4)
#define RANK_BLOCKS (RANK_N/256)
#define INV_T 14.285714285714286f
#define SHIFT 16.0f
#define MAXP  48

typedef __attribute__((ext_vector_type(8))) short bf16x8_t;
typedef __attribute__((ext_vector_type(4))) float f32x4_t;

__device__ __forceinline__ unsigned short f2bf(float f) {
  union { float fv; unsigned int u; } v; v.fv = f;
  unsigned int u = v.u;
  unsigned int r = u + 0x7FFFu + ((u >> 16) & 1u);
  return (unsigned short)(r >> 16);
}

__device__ __forceinline__ const float* zrow(const float* za, const float* zb, int g) {
  return g < HB ? za + (size_t)g * DIM : zb + (size_t)(g - HB) * DIM;
}
__device__ __forceinline__ int piece_of(const int* pa, const int* pb, int g) {
  return g < HB ? pa[g] : pb[g - HB];
}

// ---------------- K1: fused normalize->bf16 + histogram + ranking BCE ----------------
__global__ void k_pre(const float* __restrict__ za, const float* __restrict__ zb,
                      const float* __restrict__ logits, const float* __restrict__ la,
                      const float* __restrict__ lb,
                      const int* __restrict__ pa, const int* __restrict__ pb,
                      unsigned short* __restrict__ zn, int* __restrict__ hist,
                      float* __restrict__ accf) {
  __shared__ float sred[8];
  int bid = blockIdx.x;
  int t = threadIdx.x;
  if (bid < NORM_BLOCKS) {
    int lane = t & 63, w = t >> 6;
    int row = bid * 4 + w;
    const float* src = zrow(za, zb, row);
    float4 v = *reinterpret_cast<const float4*>(src + lane * 4);
    float ss = v.x * v.x + v.y * v.y + v.z * v.z + v.w * v.w;
    for (int o = 32; o; o >>= 1) ss += __shfl_xor(ss, o, 64);
    float inv = 1.0f / fmaxf(sqrtf(ss), 1e-8f);
    ushort4 o;
    o.x = f2bf(v.x * inv); o.y = f2bf(v.y * inv);
    o.z = f2bf(v.z * inv); o.w = f2bf(v.w * inv);
    *reinterpret_cast<ushort4*>(zn + (size_t)row * DIM + lane * 4) = o;
    if (lane == 0) atomicAdd(&hist[piece_of(pa, pb, row)], 1);
  } else {
    int e = (bid - NORM_BLOCKS) * 256 + t;
    float lsum = 0.f, lcnt = 0.f;
    float diff = la[e] - lb[e];
    if (fabsf(diff) >= 0.05f) {
      float x = logits[e];
      float tgt = diff > 0.f ? 0.95f : 0.05f;
      lsum = fmaxf(x, 0.f) - x * tgt + log1pf(__expf(-fabsf(x)));
      lcnt = 1.f;
    }
    for (int o = 32; o; o >>= 1) { lsum += __shfl_xor(lsum, o, 64); lcnt += __shfl_xor(lcnt, o, 64); }
    int w = t >> 6, lane = t & 63;
    if (lane == 0) { sred[w * 2] = lsum; sred[w * 2 + 1] = lcnt; }
    __syncthreads();
    if (t == 0) {
      float S = 0.f, C = 0.f;
      for (int i = 0; i < 4; ++i) { S += sred[i * 2]; C += sred[i * 2 + 1]; }
      atomicAdd(&accf[0], S);
      atomicAdd(&accf[1], C);
    }
  }
}

// ---------------- K2: Gram + neg-exp-sum + positive-sim capture ----------------
// grid 1024: it = bid>>4 (128-row i-tile), chunk = bid&15 (512-col j-range)
__global__ __launch_bounds__(256, 4)
void k_gram(const unsigned short* __restrict__ zn,
            const int* __restrict__ pa, const int* __restrict__ pb,
            float* __restrict__ neg_s, int* __restrict__ posCount,
            float* __restrict__ pos_sims) {
  __shared__ unsigned short Bs[64 * 256];  // swizzled: idx = r*256 + (c ^ ((r&7)<<3))
  __shared__ int Ps[512];
  const int t = threadIdx.x;
  const int lane = t & 63;
  const int w = t >> 6;
  const int l15 = lane & 15;
  const int lg = lane >> 4;
  const int it = blockIdx.x >> 4;
  const int chunk = blockIdx.x & 15;
  const int ibase = it * 128;
  const int jbase0 = chunk * 512;

  // stage this chunk's piece ids
  Ps[t]       = piece_of(pa, pb, jbase0 + t);
  Ps[t + 256] = piece_of(pa, pb, jbase0 + t + 256);

  // A fragments: 2 m-tiles x 8 k-steps from normalized bf16
  bf16x8_t afrag[2][8];
  for (int mt = 0; mt < 2; ++mt) {
    int garow = ibase + w * 32 + mt * 16 + l15;
    const unsigned short* asrc = zn + (size_t)garow * DIM;
    for (int ks = 0; ks < 8; ++ks)
      afrag[mt][ks] = *reinterpret_cast<const bf16x8_t*>(asrc + lg * 8 + ks * 32);
  }

  int prow[8];
  for (int mt = 0; mt < 2; ++mt)
    for (int r = 0; r < 4; ++r)
      prow[mt * 4 + r] = piece_of(pa, pb, ibase + w * 32 + mt * 16 + lg * 4 + r);

  float s[8] = {0.f, 0.f, 0.f, 0.f, 0.f, 0.f, 0.f, 0.f};

  for (int jt = 0; jt < 8; ++jt) {
    int jb = jbase0 + jt * 64;
    __syncthreads();
    // stage 64x256 bf16 tile, swizzled (16B chunks; chunk = 8 ushorts)
    for (int i = 0; i < 8; ++i) {
      int f = t + i * 256;
      int r = f >> 5;
      int c = f & 31;
      bf16x8_t v = *reinterpret_cast<const bf16x8_t*>(zn + (size_t)(jb + r) * DIM + c * 8);
      *reinterpret_cast<bf16x8_t*>(&Bs[r * 256 + ((c * 8) ^ ((r & 7) << 3))]) = v;
    }
    __syncthreads();
    for (int ct = 0; ct < 4; ++ct) {
      int jl = jt * 64 + ct * 16 + l15;
      int pc = Ps[jl];
      int jj = jbase0 + jl;
      int brow = ct * 16 + l15;
      f32x4_t acc0 = {0.f, 0.f, 0.f, 0.f};
      f32x4_t acc1 = {0.f, 0.f, 0.f, 0.f};
      for (int ks = 0; ks < 8; ++ks) {
        bf16x8_t bfrag = *reinterpret_cast<const bf16x8_t*>(
            &Bs[brow * 256 + ((lg * 8 + ks * 32) ^ ((brow & 7) << 3))]);
        acc0 = __builtin_amdgcn_mfma_f32_16x16x32_bf16(afrag[0][ks], bfrag, acc0, 0, 0, 0);
        acc1 = __builtin_amdgcn_mfma_f32_16x16x32_bf16(afrag[1][ks], bfrag, acc1, 0, 0, 0);
      }
      for (int r = 0; r < 4; ++r) {
        int gi0 = ibase + w * 32 + lg * 4 + r;
        float sim0 = acc0[r] * INV_T;
        if (pc != prow[r]) {
          s[r] += __expf(sim0 - SHIFT);
        } else if (jj != gi0) {
          int slot = atomicAdd(&posCount[gi0], 1);
          if (slot < MAXP) pos_sims[(size_t)gi0 * MAXP + slot] = sim0;
        }
        int gi1 = gi0 + 16;
        float sim1 = acc1[r] * INV_T;
        if (pc != prow[4 + r]) {
          s[4 + r] += __expf(sim1 - SHIFT);
        } else if (jj != gi1) {
          int slot = atomicAdd(&posCount[gi1], 1);
          if (slot < MAXP) pos_sims[(size_t)gi1 * MAXP + slot] = sim1;
        }
      }
    }
  }
  for (int q = 0; q < 8; ++q) {
    float v = s[q];
    v += __shfl_xor(v, 1, 64);
    v += __shfl_xor(v, 2, 64);
    v += __shfl_xor(v, 4, 64);
    v += __shfl_xor(v, 8, 64);
    if (l15 == 0)
      atomicAdd(&neg_s[ibase + w * 32 + (q >> 2) * 16 + lg * 4 + (q & 3)], v);
  }
}

// ---------------- K3: positive terms + finalize (single block) ----------------
__global__ void k_post(const int* __restrict__ pa, const int* __restrict__ pb,
                       const int* __restrict__ hist, const float* __restrict__ neg_s,
                       const int* __restrict__ posCount, const float* __restrict__ pos_sims,
                       const float* __restrict__ accf, float* __restrict__ out) {
  float lsum = 0.f, lcnt = 0.f;
  for (int i = threadIdx.x; i < NTOT; i += 256) {
    int pi = piece_of(pa, pb, i);
    int cnt = hist[pi];
    if (cnt - 1 > 0 && NTOT - cnt > 0) {
      float nlse = SHIFT + logf(neg_s[i]);
      int m = posCount[i];
      if (m > MAXP) m = MAXP;
      for (int s = 0; s < m; ++s) {
        float x = nlse - pos_sims[(size_t)i * MAXP + s];
        lsum += fmaxf(x, 0.f) + log1pf(__expf(-fabsf(x)));
      }
      lcnt += (float)(cnt - 1);
    }
  }
  for (int o = 32; o; o >>= 1) { lsum += __shfl_xor(lsum, o, 64); lcnt += __shfl_xor(lcnt, o, 64); }
  __shared__ float sred[8];
  int w = threadIdx.x >> 6, lane = threadIdx.x & 63;
  if (lane == 0) { sred[w * 2] = lsum; sred[w * 2 + 1] = lcnt; }
  __syncthreads();
  if (threadIdx.x == 0) {
    float ps = 0.f, pcn = 0.f;
    for (int i = 0; i < 4; ++i) { ps += sred[i * 2]; pcn += sred[i * 2 + 1]; }
    float rs = accf[0], rc = accf[1];
    float l_rank = rc > 0.f ? rs / rc : 0.f;
    float l_con = pcn > 0.f ? ps / pcn : 0.f;
    out[0] = l_rank + 0.3f * l_con;
    out[1] = l_rank;
    out[2] = l_con;
  }
}

extern "C" void kernel_launch(void* const* d_in, const int* in_sizes, int n_in,
                              void* d_out, int out_size, void* d_ws, size_t ws_size,
                              hipStream_t stream) {
  const float* za     = (const float*)d_in[0];
  const float* zb     = (const float*)d_in[1];
  const float* logits = (const float*)d_in[2];
  const float* la     = (const float*)d_in[3];
  const float* lb     = (const float*)d_in[4];
  const int*   pa     = (const int*)d_in[5];
  const int*   pb     = (const int*)d_in[6];
  float* out = (float*)d_out;

  // ws layout (floats):
  //   [0..4)          accf: rank_sum, rank_cnt, (unused x2)
  //   [4 .. 4+8192)   neg_s
  //   next 1024 (int) hist
  //   next 8192 (int) posCount
  //   next 8192*MAXP  pos_sims
  //   next 8192*256   zn (bf16)
  float* wsf = (float*)d_ws;
  int*   wsi = (int*)d_ws;
  float* neg_s    = wsf + 4;
  int*   hist     = wsi + 4 + NTOT;
  int*   posCount = wsi + 4 + NTOT + 1024;
  float* pos_sims = wsf + 4 + NTOT + 1024 + NTOT;
  unsigned short* zn = (unsigned short*)(wsf + 4 + NTOT + 1024 + NTOT + (size_t)NTOT * MAXP);

  hipMemsetAsync(d_ws, 0, (size_t)(4 + NTOT + 1024 + NTOT) * 4, stream);
  k_pre<<<NORM_BLOCKS + RANK_BLOCKS, 256, 0, stream>>>(za, zb, logits, la, lb, pa, pb, zn, hist, wsf);
  k_gram<<<1024, 256, 0, stream>>>(zn, pa, pb, neg_s, posCount, pos_sims);
  k_post<<<1, 256, 0, stream>>>(pa, pb, hist, neg_s, posCount, pos_sims, wsf, out);
}

// Round 5
// 164.851 us; speedup vs baseline: 2.2924x; 2.2924x over previous
//
#include <hip/hip_runtime.h>
#include <hip/hip_bf16.h>
#include <math.h>

#define NTOT 8192
#define HB   4096
#define DIM  256
#define RANK_N (4096*19)
#define NORM_BLOCKS (NTOT/4)
#define RANK_BLOCKS (RANK_N/256)
#define INV_T 14.285714285714286f
#define SHIFT 16.0f
#define MAXP  48

typedef __attribute__((ext_vector_type(8))) short bf16x8_t;
typedef __attribute__((ext_vector_type(4))) float f32x4_t;

__device__ __forceinline__ unsigned short f2bf(float f) {
  union { float fv; unsigned int u; } v; v.fv = f;
  unsigned int u = v.u;
  unsigned int r = u + 0x7FFFu + ((u >> 16) & 1u);
  return (unsigned short)(r >> 16);
}

__device__ __forceinline__ const float* zrow(const float* za, const float* zb, int g) {
  return g < HB ? za + (size_t)g * DIM : zb + (size_t)(g - HB) * DIM;
}
__device__ __forceinline__ int piece_of(const int* pa, const int* pb, int g) {
  return g < HB ? pa[g] : pb[g - HB];
}

// ---------------- K1: fused normalize->bf16 + histogram + ranking BCE ----------------
__global__ void k_pre(const float* __restrict__ za, const float* __restrict__ zb,
                      const float* __restrict__ logits, const float* __restrict__ la,
                      const float* __restrict__ lb,
                      const int* __restrict__ pa, const int* __restrict__ pb,
                      unsigned short* __restrict__ zn, int* __restrict__ hist,
                      float* __restrict__ accf) {
  __shared__ float sred[8];
  int bid = blockIdx.x;
  int t = threadIdx.x;
  if (bid < NORM_BLOCKS) {
    int lane = t & 63, w = t >> 6;
    int row = bid * 4 + w;
    const float* src = zrow(za, zb, row);
    float4 v = *reinterpret_cast<const float4*>(src + lane * 4);
    float ss = v.x * v.x + v.y * v.y + v.z * v.z + v.w * v.w;
    for (int o = 32; o; o >>= 1) ss += __shfl_xor(ss, o, 64);
    float inv = 1.0f / fmaxf(sqrtf(ss), 1e-8f);
    ushort4 o;
    o.x = f2bf(v.x * inv); o.y = f2bf(v.y * inv);
    o.z = f2bf(v.z * inv); o.w = f2bf(v.w * inv);
    *reinterpret_cast<ushort4*>(zn + (size_t)row * DIM + lane * 4) = o;
    if (lane == 0) atomicAdd(&hist[piece_of(pa, pb, row)], 1);
  } else {
    int e = (bid - NORM_BLOCKS) * 256 + t;
    float lsum = 0.f, lcnt = 0.f;
    float diff = la[e] - lb[e];
    if (fabsf(diff) >= 0.05f) {
      float x = logits[e];
      float tgt = diff > 0.f ? 0.95f : 0.05f;
      lsum = fmaxf(x, 0.f) - x * tgt + log1pf(__expf(-fabsf(x)));
      lcnt = 1.f;
    }
    for (int o = 32; o; o >>= 1) { lsum += __shfl_xor(lsum, o, 64); lcnt += __shfl_xor(lcnt, o, 64); }
    int w = t >> 6, lane = t & 63;
    if (lane == 0) { sred[w * 2] = lsum; sred[w * 2 + 1] = lcnt; }
    __syncthreads();
    if (t == 0) {
      float S = 0.f, C = 0.f;
      for (int i = 0; i < 4; ++i) { S += sred[i * 2]; C += sred[i * 2 + 1]; }
      atomicAdd(&accf[0], S);
      atomicAdd(&accf[1], C);
    }
  }
}

// ---------------- K2: Gram + neg-exp-sum + positive-sim capture ----------------
// grid 1024: it = bid>>4 (128-row i-tile), chunk = bid&15 (512-col j-range)
__global__ __launch_bounds__(256, 4)
void k_gram(const unsigned short* __restrict__ zn,
            const int* __restrict__ pa, const int* __restrict__ pb,
            float* __restrict__ neg_s, int* __restrict__ posCount,
            float* __restrict__ pos_sims) {
  __shared__ unsigned short Bs[64 * 256];  // swizzled: idx = r*256 + (c ^ ((r&7)<<3))
  __shared__ int Ps[512];
  const int t = threadIdx.x;
  const int lane = t & 63;
  const int w = t >> 6;
  const int l15 = lane & 15;
  const int lg = lane >> 4;
  const int it = blockIdx.x >> 4;
  const int chunk = blockIdx.x & 15;
  const int ibase = it * 128;
  const int jbase0 = chunk * 512;

  // stage this chunk's piece ids
  Ps[t]       = piece_of(pa, pb, jbase0 + t);
  Ps[t + 256] = piece_of(pa, pb, jbase0 + t + 256);

  // A fragments: 2 m-tiles x 8 k-steps from normalized bf16
  bf16x8_t afrag[2][8];
  for (int mt = 0; mt < 2; ++mt) {
    int garow = ibase + w * 32 + mt * 16 + l15;
    const unsigned short* asrc = zn + (size_t)garow * DIM;
    for (int ks = 0; ks < 8; ++ks)
      afrag[mt][ks] = *reinterpret_cast<const bf16x8_t*>(asrc + lg * 8 + ks * 32);
  }

  int prow[8];
  for (int mt = 0; mt < 2; ++mt)
    for (int r = 0; r < 4; ++r)
      prow[mt * 4 + r] = piece_of(pa, pb, ibase + w * 32 + mt * 16 + lg * 4 + r);

  float s[8] = {0.f, 0.f, 0.f, 0.f, 0.f, 0.f, 0.f, 0.f};

  for (int jt = 0; jt < 8; ++jt) {
    int jb = jbase0 + jt * 64;
    __syncthreads();
    // stage 64x256 bf16 tile, swizzled (16B chunks; chunk = 8 ushorts)
    for (int i = 0; i < 8; ++i) {
      int f = t + i * 256;
      int r = f >> 5;
      int c = f & 31;
      bf16x8_t v = *reinterpret_cast<const bf16x8_t*>(zn + (size_t)(jb + r) * DIM + c * 8);
      *reinterpret_cast<bf16x8_t*>(&Bs[r * 256 + ((c * 8) ^ ((r & 7) << 3))]) = v;
    }
    __syncthreads();
    for (int ct = 0; ct < 4; ++ct) {
      int jl = jt * 64 + ct * 16 + l15;
      int pc = Ps[jl];
      int jj = jbase0 + jl;
      int brow = ct * 16 + l15;
      f32x4_t acc0 = {0.f, 0.f, 0.f, 0.f};
      f32x4_t acc1 = {0.f, 0.f, 0.f, 0.f};
      for (int ks = 0; ks < 8; ++ks) {
        bf16x8_t bfrag = *reinterpret_cast<const bf16x8_t*>(
            &Bs[brow * 256 + ((lg * 8 + ks * 32) ^ ((brow & 7) << 3))]);
        acc0 = __builtin_amdgcn_mfma_f32_16x16x32_bf16(afrag[0][ks], bfrag, acc0, 0, 0, 0);
        acc1 = __builtin_amdgcn_mfma_f32_16x16x32_bf16(afrag[1][ks], bfrag, acc1, 0, 0, 0);
      }
      for (int r = 0; r < 4; ++r) {
        int gi0 = ibase + w * 32 + lg * 4 + r;
        float sim0 = acc0[r] * INV_T;
        if (pc != prow[r]) {
          s[r] += __expf(sim0 - SHIFT);
        } else if (jj != gi0) {
          int slot = atomicAdd(&posCount[gi0], 1);
          if (slot < MAXP) pos_sims[(size_t)gi0 * MAXP + slot] = sim0;
        }
        int gi1 = gi0 + 16;
        float sim1 = acc1[r] * INV_T;
        if (pc != prow[4 + r]) {
          s[4 + r] += __expf(sim1 - SHIFT);
        } else if (jj != gi1) {
          int slot = atomicAdd(&posCount[gi1], 1);
          if (slot < MAXP) pos_sims[(size_t)gi1 * MAXP + slot] = sim1;
        }
      }
    }
  }
  for (int q = 0; q < 8; ++q) {
    float v = s[q];
    v += __shfl_xor(v, 1, 64);
    v += __shfl_xor(v, 2, 64);
    v += __shfl_xor(v, 4, 64);
    v += __shfl_xor(v, 8, 64);
    if (l15 == 0)
      atomicAdd(&neg_s[ibase + w * 32 + (q >> 2) * 16 + lg * 4 + (q & 3)], v);
  }
}

// ---------------- K3: positive-pair terms (one anchor per thread, 32 blocks) ----------------
__global__ void k_pos2(const int* __restrict__ pa, const int* __restrict__ pb,
                       const int* __restrict__ hist, const float* __restrict__ neg_s,
                       const int* __restrict__ posCount, const float* __restrict__ pos_sims,
                       float* __restrict__ accf) {
  int i = blockIdx.x * 256 + threadIdx.x;  // grid covers NTOT exactly
  float lsum = 0.f, lcnt = 0.f;
  int pi = piece_of(pa, pb, i);
  int cnt = hist[pi];
  if (cnt - 1 > 0 && NTOT - cnt > 0) {
    float nlse = SHIFT + logf(neg_s[i]);
    int m = posCount[i];
    if (m > MAXP) m = MAXP;
    for (int s = 0; s < m; ++s) {
      float x = nlse - pos_sims[(size_t)i * MAXP + s];
      lsum += fmaxf(x, 0.f) + log1pf(__expf(-fabsf(x)));
    }
    lcnt = (float)(cnt - 1);
  }
  for (int o = 32; o; o >>= 1) { lsum += __shfl_xor(lsum, o, 64); lcnt += __shfl_xor(lcnt, o, 64); }
  int lane = threadIdx.x & 63;
  if (lane == 0) {
    atomicAdd(&accf[2], lsum);
    atomicAdd(&accf[3], lcnt);
  }
}

// ---------------- K4: finalize ----------------
__global__ void k_final(const float* __restrict__ accf, float* __restrict__ out) {
  float rs = accf[0], rc = accf[1], ps = accf[2], pcn = accf[3];
  float l_rank = rc > 0.f ? rs / rc : 0.f;
  float l_con = pcn > 0.f ? ps / pcn : 0.f;
  out[0] = l_rank + 0.3f * l_con;
  out[1] = l_rank;
  out[2] = l_con;
}

extern "C" void kernel_launch(void* const* d_in, const int* in_sizes, int n_in,
                              void* d_out, int out_size, void* d_ws, size_t ws_size,
                              hipStream_t stream) {
  const float* za     = (const float*)d_in[0];
  const float* zb     = (const float*)d_in[1];
  const float* logits = (const float*)d_in[2];
  const float* la     = (const float*)d_in[3];
  const float* lb     = (const float*)d_in[4];
  const int*   pa     = (const int*)d_in[5];
  const int*   pb     = (const int*)d_in[6];
  float* out = (float*)d_out;

  // ws layout (floats):
  //   [0..4)          accf: rank_sum, rank_cnt, pos_sum, pos_cnt
  //   [4 .. 4+8192)   neg_s
  //   next 1024 (int) hist
  //   next 8192 (int) posCount
  //   next 8192*MAXP  pos_sims
  //   next 8192*256   zn (bf16)
  float* wsf = (float*)d_ws;
  int*   wsi = (int*)d_ws;
  float* neg_s    = wsf + 4;
  int*   hist     = wsi + 4 + NTOT;
  int*   posCount = wsi + 4 + NTOT + 1024;
  float* pos_sims = wsf + 4 + NTOT + 1024 + NTOT;
  unsigned short* zn = (unsigned short*)(wsf + 4 + NTOT + 1024 + NTOT + (size_t)NTOT * MAXP);

  hipMemsetAsync(d_ws, 0, (size_t)(4 + NTOT + 1024 + NTOT) * 4, stream);
  k_pre<<<NORM_BLOCKS + RANK_BLOCKS, 256, 0, stream>>>(za, zb, logits, la, lb, pa, pb, zn, hist, wsf);
  k_gram<<<1024, 256, 0, stream>>>(zn, pa, pb, neg_s, posCount, pos_sims);
  k_pos2<<<NTOT / 256, 256, 0, stream>>>(pa, pb, hist, neg_s, posCount, pos_sims, wsf);
  k_final<<<1, 1, 0, stream>>>(wsf, out);
}